// Round 2
// baseline (232.266 us; speedup 1.0000x reference)
//
#include <hip/hip_runtime.h>
#include <cstdint>

#define NB 4
#define ND 1024
#define NT 2048
#define NH 16
#define NE 64
#define GLEN 2240  // per-copy length of reversed Toeplitz table (elements)

typedef __bf16 bf16x8 __attribute__((ext_vector_type(8)));
typedef float f32x4 __attribute__((ext_vector_type(4)));
typedef unsigned short us8 __attribute__((ext_vector_type(8)));

__device__ __forceinline__ unsigned short f2bf(float f) {
  unsigned u = __builtin_bit_cast(unsigned, f);
  return (unsigned short)((u + 0x7fffu + ((u >> 16) & 1u)) >> 16);  // RTNE
}

// async global->LDS, 16B per lane; LDS dest must be wave-uniform base + lane*16
__device__ __forceinline__ void gload16(const void* g, void* l) {
  __builtin_amdgcn_global_load_lds(
      (const __attribute__((address_space(1))) void*)(uintptr_t)g,
      (__attribute__((address_space(3))) void*)(uintptr_t)l, 16, 0, 0);
}

// ---------------------------------------------------------------- prep ------
// Cast Wp, Wo to bf16; build 8-copy reversed Toeplitz table:
//   R[c] = bf16(tw[h][2047-c]) for c<=2047 else 0   (c>2047 <=> t-s<0: causal 0)
//   Gr8[h][r][i] = R[i+r]  so any 8-consecutive-element read lands 16B-aligned
//   in copy r = start&7.
__global__ void prep_kernel(const float* __restrict__ Wp, const float* __restrict__ Wo,
                            const float* __restrict__ tw,
                            unsigned short* __restrict__ WpB, unsigned short* __restrict__ WoB,
                            unsigned short* __restrict__ Gr8) {
  int idx = blockIdx.x * 256 + threadIdx.x;
  int stride = gridDim.x * 256;
  for (int i = idx; i < ND * ND; i += stride) WpB[i] = f2bf(Wp[i]);
  for (int i = idx; i < ND * ND; i += stride) WoB[i] = f2bf(Wo[i]);
  for (int i = idx; i < NH * 8 * GLEN; i += stride) {
    int h = i / (8 * GLEN);
    int rem = i - h * 8 * GLEN;
    int r = rem / GLEN;
    int c = rem - r * GLEN;
    int src = c + r;
    Gr8[i] = (src <= NT - 1) ? f2bf(tw[h * NT + (NT - 1) - src]) : (unsigned short)0;
  }
}

// ------------------------------------------------------- transpose + cast ---
// x (B,D,T) f32 -> xT (B,T,D) bf16. 32x32 LDS tile.
__global__ __launch_bounds__(256) void transpose_cast(const float* __restrict__ x,
                                                      unsigned short* __restrict__ xT) {
  __shared__ float tile[32][33];
  int tx = threadIdx.x & 31, ty = threadIdx.x >> 5;  // ty in 0..7
  int t0 = blockIdx.x * 32, d0 = blockIdx.y * 32, b = blockIdx.z;
  const float* xb = x + (long)b * ND * NT;
#pragma unroll
  for (int k = 0; k < 4; ++k)
    tile[ty + 8 * k][tx] = xb[(long)(d0 + ty + 8 * k) * NT + t0 + tx];
  __syncthreads();
  unsigned short* xTb = xT + (long)b * NT * ND;
#pragma unroll
  for (int k = 0; k < 4; ++k)
    xTb[(long)(t0 + ty + 8 * k) * ND + d0 + tx] = f2bf(tile[tx][ty + 8 * k]);
}

// ----------------------------------------------------------- gemm_bt --------
// C[b][m][n] = sum_k A[m][k] * Bt[b][n][k] + bias[m]
// M=1024, N=2048, K=1024. 128x128 tile, BK=32, 4 waves of 64x64, 16x16x32 MFMA.
template <bool OUT_BF16>
__global__ __launch_bounds__(256, 2) void gemm_bt(const unsigned short* __restrict__ A,
                                                  const unsigned short* __restrict__ Bt,
                                                  const float* __restrict__ bias,
                                                  void* __restrict__ Cb, long strideB,
                                                  long strideC) {
  const int N = 2048, K = 1024;
  __shared__ __align__(16) unsigned short As[128 * 32];
  __shared__ __align__(16) unsigned short Bs[128 * 32];
  const int tid = threadIdx.x;
  const int lane = tid & 63;
  const int wid = tid >> 6;
  const int wm = (wid & 1) * 64, wn = (wid >> 1) * 64;
  const int m0 = blockIdx.y * 128, n0 = blockIdx.x * 128;
  const unsigned short* Bb = Bt + (long)blockIdx.z * strideB;
  const int mlo = lane & 15, q = lane >> 4;

  f32x4 acc[4][4] = {};
  for (int k0 = 0; k0 < K; k0 += 32) {
#pragma unroll
    for (int p = 0; p < 2; ++p) {
      int idx = p * 256 + tid;
      int row = idx >> 2, kc = (idx & 3) * 8;
      gload16(A + (long)(m0 + row) * K + k0 + kc, &As[idx * 8]);
      gload16(Bb + (long)(n0 + row) * K + k0 + kc, &Bs[idx * 8]);
    }
    __syncthreads();
    bf16x8 av[4], bv[4];
#pragma unroll
    for (int i = 0; i < 4; ++i) {
      av[i] = __builtin_bit_cast(bf16x8, *(const us8*)&As[(wm + i * 16 + mlo) * 32 + q * 8]);
      bv[i] = __builtin_bit_cast(bf16x8, *(const us8*)&Bs[(wn + i * 16 + mlo) * 32 + q * 8]);
    }
#pragma unroll
    for (int i = 0; i < 4; ++i)
#pragma unroll
      for (int j = 0; j < 4; ++j)
        acc[i][j] = __builtin_amdgcn_mfma_f32_16x16x32_bf16(av[i], bv[j], acc[i][j], 0, 0, 0);
    __syncthreads();
  }
  // epilogue: C/D layout col=lane&15, row=(lane>>4)*4+r
#pragma unroll
  for (int i = 0; i < 4; ++i)
#pragma unroll
    for (int j = 0; j < 4; ++j)
#pragma unroll
      for (int r = 0; r < 4; ++r) {
        int gr = m0 + wm + i * 16 + q * 4 + r;
        int gc = n0 + wn + j * 16 + mlo;
        float v = acc[i][j][r] + bias[gr];
        if (OUT_BF16)
          ((unsigned short*)Cb)[(long)blockIdx.z * strideC + (long)gr * N + gc] = f2bf(v);
        else
          ((float*)Cb)[(long)blockIdx.z * strideC + (long)gr * N + gc] = v;
      }
}

// ----------------------------------------------------------- toeplitz -------
// mixedT[b][t][h*64+e] = sum_{s<=t} tw[h][t-s] * proj[b][h*64+e][s]
// Block: 128 t x 128 n (n = 2 batches x 64 e), 4 waves in 2x2, each 64t x 64n.
// A-fragments come straight from the 8-copy reversed global table Gr8 as one
// aligned global_load_dwordx4 per fragment (no LDS, no pack VALU, causality
// baked in as zeros). B staged via global_load_lds. Longest t-tiles first.
__global__ __launch_bounds__(256, 2) void toeplitz(const unsigned short* __restrict__ proj,
                                                   const unsigned short* __restrict__ Gr8,
                                                   unsigned short* __restrict__ mixedT) {
  __shared__ __align__(16) unsigned short Bs[128 * 32];
  const int tid = threadIdx.x, lane = tid & 63, w = tid >> 6;
  const int t0 = ((int)gridDim.x - 1 - (int)blockIdx.x) * 128;  // longest first
  const int h = blockIdx.y, zb = blockIdx.z;  // zb 0..1 (batch pair)
  const int mlo = lane & 15, q = lane >> 4;
  const int wt = (w & 1) * 64, wn = (w >> 1) * 64;

  // per-lane copy selector; constant across k-iters and i (s0,q*8,i*16 all ≡0 mod 8)
  const int r = (7 - mlo) & 7;
  // element j of av[i] at k-chunk s0 = Gr8_copy_r[(2047 - mlo - r) - t0 - wt - i*16 + q*8 + s0 + j]
  const unsigned short* gA =
      Gr8 + (long)(h * 8 + r) * GLEN + ((NT - 1) - mlo - r) - t0 - wt + q * 8;

  f32x4 acc[4][4] = {};
  const int kend = t0 + 128;
  for (int s0 = 0; s0 < kend; s0 += 32) {
#pragma unroll
    for (int p = 0; p < 2; ++p) {
      int idx = p * 256 + tid;
      int n = idx >> 2, kc = (idx & 3) * 8;  // n in 0..127
      int bb = n >> 6, e = n & 63;
      gload16(proj + ((long)(zb * 2 + bb) * ND + h * 64 + e) * NT + s0 + kc, &Bs[idx * 8]);
    }
    __syncthreads();
    bf16x8 av[4], bv[4];
#pragma unroll
    for (int i = 0; i < 4; ++i)
      av[i] = __builtin_bit_cast(bf16x8, *(const us8*)(gA + s0 - i * 16));
#pragma unroll
    for (int j = 0; j < 4; ++j)
      bv[j] = __builtin_bit_cast(bf16x8, *(const us8*)&Bs[(wn + j * 16 + mlo) * 32 + q * 8]);
#pragma unroll
    for (int i = 0; i < 4; ++i)
#pragma unroll
      for (int j = 0; j < 4; ++j)
        acc[i][j] = __builtin_amdgcn_mfma_f32_16x16x32_bf16(av[i], bv[j], acc[i][j], 0, 0, 0);
    __syncthreads();
  }
#pragma unroll
  for (int i = 0; i < 4; ++i)
#pragma unroll
    for (int j = 0; j < 4; ++j)
#pragma unroll
      for (int rr = 0; rr < 4; ++rr) {
        int t = t0 + wt + i * 16 + q * 4 + rr;
        int n = wn + j * 16 + mlo;
        int bb = n >> 6, e = n & 63;
        mixedT[((long)(zb * 2 + bb) * NT + t) * ND + h * 64 + e] = f2bf(acc[i][j][rr]);
      }
}

// ---------------------------------------------------------------------------
extern "C" void kernel_launch(void* const* d_in, const int* in_sizes, int n_in, void* d_out,
                              int out_size, void* d_ws, size_t ws_size, hipStream_t stream) {
  const float* x = (const float*)d_in[0];
  const float* Wp = (const float*)d_in[1];
  const float* bp = (const float*)d_in[2];
  const float* tw = (const float*)d_in[3];
  const float* Wo = (const float*)d_in[4];
  const float* bo = (const float*)d_in[5];
  float* out = (float*)d_out;

  char* ws = (char*)d_ws;
  // layout (bytes): [0,16M) xT / mixedT (reused)  [16M,32M) proj
  //                 [32M,34M) WpB  [34M,36M) WoB  [36M,+0.6M) Gr8
  unsigned short* xT = (unsigned short*)(ws);  // also mixedT after stage 2
  unsigned short* proj = (unsigned short*)(ws + (16ull << 20));
  unsigned short* WpB = (unsigned short*)(ws + (32ull << 20));
  unsigned short* WoB = (unsigned short*)(ws + (34ull << 20));
  unsigned short* Gr8 = (unsigned short*)(ws + (36ull << 20));

  prep_kernel<<<dim3(2048), 256, 0, stream>>>(Wp, Wo, tw, WpB, WoB, Gr8);
  transpose_cast<<<dim3(NT / 32, ND / 32, NB), 256, 0, stream>>>(x, xT);
  // stage 1: proj[b][he][t] = Wp @ x[b] + bp
  gemm_bt<true><<<dim3(16, 8, NB), 256, 0, stream>>>(WpB, xT, bp, proj, (long)NT * ND,
                                                     (long)ND * NT);
  // stage 2: mixedT[b][t][he] (written into xT buffer)
  toeplitz<<<dim3(NT / 128, NH, NB / 2), 256, 0, stream>>>(proj, Gr8, xT);
  // stage 3: out[b][d][t] = Wo @ mixedT[b]^T + bo
  gemm_bt<false><<<dim3(16, 8, NB), 256, 0, stream>>>(WoB, xT, bo, out, (long)NT * ND,
                                                      (long)ND * NT);
}

// Round 3
// 189.364 us; speedup vs baseline: 1.2266x; 1.2266x over previous
//
#include <hip/hip_runtime.h>
#include <cstdint>

#define NB 4
#define ND 1024
#define NT 2048
#define NH 16
#define NE 64
#define GLEN 2240  // per-copy length of reversed global Toeplitz table (elements)
#define CAP 2312   // per-copy length of LDS table (elements); 4624B = 4-bank shift/copy

typedef __bf16 bf16x8 __attribute__((ext_vector_type(8)));
typedef float f32x4 __attribute__((ext_vector_type(4)));
typedef unsigned short us8 __attribute__((ext_vector_type(8)));

__device__ __forceinline__ unsigned short f2bf(float f) {
  unsigned u = __builtin_bit_cast(unsigned, f);
  return (unsigned short)((u + 0x7fffu + ((u >> 16) & 1u)) >> 16);  // RTNE
}

// async global->LDS, 16B per lane; LDS dest must be wave-uniform base + lane*16
__device__ __forceinline__ void gload16(const void* g, void* l) {
  __builtin_amdgcn_global_load_lds(
      (const __attribute__((address_space(1))) void*)(uintptr_t)g,
      (__attribute__((address_space(3))) void*)(uintptr_t)l, 16, 0, 0);
}

// ---------------------------------------------------------------- prep ------
// Cast Wp, Wo to bf16; build 8-copy reversed Toeplitz table:
//   R[c] = bf16(tw[h][2047-c]) for c<=2047 else 0   (c>2047 <=> t-s<0: causal 0)
//   Gr8[h][r][i] = R[i+r]  so any 8-consecutive-element read lands 16B-aligned
//   in copy r = start&7.
__global__ void prep_kernel(const float* __restrict__ Wp, const float* __restrict__ Wo,
                            const float* __restrict__ tw,
                            unsigned short* __restrict__ WpB, unsigned short* __restrict__ WoB,
                            unsigned short* __restrict__ Gr8) {
  int idx = blockIdx.x * 256 + threadIdx.x;
  int stride = gridDim.x * 256;
  for (int i = idx; i < ND * ND; i += stride) WpB[i] = f2bf(Wp[i]);
  for (int i = idx; i < ND * ND; i += stride) WoB[i] = f2bf(Wo[i]);
  for (int i = idx; i < NH * 8 * GLEN; i += stride) {
    int h = i / (8 * GLEN);
    int rem = i - h * 8 * GLEN;
    int r = rem / GLEN;
    int c = rem - r * GLEN;
    int src = c + r;
    Gr8[i] = (src <= NT - 1) ? f2bf(tw[h * NT + (NT - 1) - src]) : (unsigned short)0;
  }
}

// ------------------------------------------------------- transpose + cast ---
// x (B,D,T) f32 -> xT (B,T,D) bf16. 32x32 LDS tile.
__global__ __launch_bounds__(256) void transpose_cast(const float* __restrict__ x,
                                                      unsigned short* __restrict__ xT) {
  __shared__ float tile[32][33];
  int tx = threadIdx.x & 31, ty = threadIdx.x >> 5;  // ty in 0..7
  int t0 = blockIdx.x * 32, d0 = blockIdx.y * 32, b = blockIdx.z;
  const float* xb = x + (long)b * ND * NT;
#pragma unroll
  for (int k = 0; k < 4; ++k)
    tile[ty + 8 * k][tx] = xb[(long)(d0 + ty + 8 * k) * NT + t0 + tx];
  __syncthreads();
  unsigned short* xTb = xT + (long)b * NT * ND;
#pragma unroll
  for (int k = 0; k < 4; ++k)
    xTb[(long)(t0 + ty + 8 * k) * ND + d0 + tx] = f2bf(tile[tx][ty + 8 * k]);
}

// ----------------------------------------------------------- gemm_bt --------
// C[b][m][n] = sum_k A[m][k] * Bt[b][n][k] + bias[m]
// M=1024, N=2048, K=1024. 128x128 tile, BK=32, 4 waves of 64x64, 16x16x32 MFMA.
template <bool OUT_BF16>
__global__ __launch_bounds__(256, 2) void gemm_bt(const unsigned short* __restrict__ A,
                                                  const unsigned short* __restrict__ Bt,
                                                  const float* __restrict__ bias,
                                                  void* __restrict__ Cb, long strideB,
                                                  long strideC) {
  const int N = 2048, K = 1024;
  __shared__ __align__(16) unsigned short As[128 * 32];
  __shared__ __align__(16) unsigned short Bs[128 * 32];
  const int tid = threadIdx.x;
  const int lane = tid & 63;
  const int wid = tid >> 6;
  const int wm = (wid & 1) * 64, wn = (wid >> 1) * 64;
  const int m0 = blockIdx.y * 128, n0 = blockIdx.x * 128;
  const unsigned short* Bb = Bt + (long)blockIdx.z * strideB;
  const int mlo = lane & 15, q = lane >> 4;

  f32x4 acc[4][4] = {};
  for (int k0 = 0; k0 < K; k0 += 32) {
#pragma unroll
    for (int p = 0; p < 2; ++p) {
      int idx = p * 256 + tid;
      int row = idx >> 2, kc = (idx & 3) * 8;
      gload16(A + (long)(m0 + row) * K + k0 + kc, &As[idx * 8]);
      gload16(Bb + (long)(n0 + row) * K + k0 + kc, &Bs[idx * 8]);
    }
    __syncthreads();
    bf16x8 av[4], bv[4];
#pragma unroll
    for (int i = 0; i < 4; ++i) {
      av[i] = __builtin_bit_cast(bf16x8, *(const us8*)&As[(wm + i * 16 + mlo) * 32 + q * 8]);
      bv[i] = __builtin_bit_cast(bf16x8, *(const us8*)&Bs[(wn + i * 16 + mlo) * 32 + q * 8]);
    }
#pragma unroll
    for (int i = 0; i < 4; ++i)
#pragma unroll
      for (int j = 0; j < 4; ++j)
        acc[i][j] = __builtin_amdgcn_mfma_f32_16x16x32_bf16(av[i], bv[j], acc[i][j], 0, 0, 0);
    __syncthreads();
  }
  // epilogue: C/D layout col=lane&15, row=(lane>>4)*4+r
#pragma unroll
  for (int i = 0; i < 4; ++i)
#pragma unroll
    for (int j = 0; j < 4; ++j)
#pragma unroll
      for (int r = 0; r < 4; ++r) {
        int gr = m0 + wm + i * 16 + q * 4 + r;
        int gc = n0 + wn + j * 16 + mlo;
        float v = acc[i][j][r] + bias[gr];
        if (OUT_BF16)
          ((unsigned short*)Cb)[(long)blockIdx.z * strideC + (long)gr * N + gc] = f2bf(v);
        else
          ((float*)Cb)[(long)blockIdx.z * strideC + (long)gr * N + gc] = v;
      }
}

// ----------------------------------------------------------- toeplitz -------
// mixedT[b][t][h*64+e] = sum_{s<=t} tw[h][t-s] * proj[b][h*64+e][s]
// Block: 128 t x 128 n (n = 2 batches x 64 e), 4 waves in 2x2, each 64t x 64n.
// A comes from an 8-copy block-local reversed table in LDS (filled once from
// the global Gr8 via global_load_lds), so every A-fragment is one 16B-aligned
// ds_read_b128 — same per-iter mix as gemm_bt (8 b128 + 2 gload16 + 16 MFMA).
// LDS copy r holds Rev[m+r], Rev[c] = bf16(tw[h][t0+127-c]) (0 when negative),
// so av[i] elem j = Rev[cbase+j] with cbase ≡ (7-mlo) mod 8 → copy r=(7-mlo)&7
// makes the read aligned. Causality is the zero padding.
__global__ __launch_bounds__(256, 3) void toeplitz(const unsigned short* __restrict__ proj,
                                                   const unsigned short* __restrict__ Gr8,
                                                   unsigned short* __restrict__ mixedT) {
  __shared__ __align__(16) unsigned short Ls[8 * CAP];   // 36992 B
  __shared__ __align__(16) unsigned short Bs[128 * 32];  // 8192 B
  const int tid = threadIdx.x, lane = tid & 63, w = tid >> 6;
  const int t0 = ((int)gridDim.x - 1 - (int)blockIdx.x) * 128;  // longest first
  const int h = blockIdx.y, zb = blockIdx.z;                    // zb 0..1 (batch pair)
  const int mlo = lane & 15, q = lane >> 4;
  const int wt = (w & 1) * 64, wn = (w >> 1) * 64;

  // ---- one-time LDS fill: Ls[r][m] = Rev[m+r] = R[m+r+delta], delta = 1920-t0
  // R[i'] lives in Gr8[h][rr][i'-rr]; pick rr=(r+delta)&7 so the global read
  // offset off8 = r+delta-rr is a multiple of 8 (16B-aligned on both sides).
  const int delta = (NT - 128) - t0;
  const int MUSE = t0 + 256;  // elements needed per copy (multiple of 8)
#pragma unroll 1
  for (int r = 0; r < 8; ++r) {
    int rr = (r + delta) & 7;
    int off8 = r + delta - rr;
    const unsigned short* src = Gr8 + (long)(h * 8 + rr) * GLEN + off8;
    unsigned short* dst = &Ls[r * CAP];
    for (int mc = tid; mc * 8 < MUSE; mc += 256) gload16(src + mc * 8, &dst[mc * 8]);
  }

  // A-fragment base: av[i] elem j = Ls[rA*CAP + (cbase - rA) + j],
  // cbase = 127 - wt - i*16 - mlo + s0 + q*8  (>=0 for all i,s0 used)
  const int rA = (7 - mlo) & 7;
  const unsigned short* lA = &Ls[rA * CAP + (127 - wt - mlo - rA) + q * 8];

  f32x4 acc[4][4] = {};
  const int kend = t0 + 128;
  for (int s0 = 0; s0 < kend; s0 += 32) {
#pragma unroll
    for (int p = 0; p < 2; ++p) {
      int idx = p * 256 + tid;
      int n = idx >> 2, kc = (idx & 3) * 8;  // n in 0..127
      int bb = n >> 6, e = n & 63;
      gload16(proj + ((long)(zb * 2 + bb) * ND + h * 64 + e) * NT + s0 + kc, &Bs[idx * 8]);
    }
    __syncthreads();  // also drains the one-time Ls fill on iter 0
    bf16x8 av[4], bv[4];
#pragma unroll
    for (int i = 0; i < 4; ++i)
      av[i] = __builtin_bit_cast(bf16x8, *(const us8*)(lA + s0 - i * 16));
#pragma unroll
    for (int j = 0; j < 4; ++j)
      bv[j] = __builtin_bit_cast(bf16x8, *(const us8*)&Bs[(wn + j * 16 + mlo) * 32 + q * 8]);
#pragma unroll
    for (int i = 0; i < 4; ++i)
#pragma unroll
      for (int j = 0; j < 4; ++j)
        acc[i][j] = __builtin_amdgcn_mfma_f32_16x16x32_bf16(av[i], bv[j], acc[i][j], 0, 0, 0);
    __syncthreads();
  }
#pragma unroll
  for (int i = 0; i < 4; ++i)
#pragma unroll
    for (int j = 0; j < 4; ++j)
#pragma unroll
      for (int rr = 0; rr < 4; ++rr) {
        int t = t0 + wt + i * 16 + q * 4 + rr;
        int n = wn + j * 16 + mlo;
        int bb = n >> 6, e = n & 63;
        mixedT[((long)(zb * 2 + bb) * NT + t) * ND + h * 64 + e] = f2bf(acc[i][j][rr]);
      }
}

// ---------------------------------------------------------------------------
extern "C" void kernel_launch(void* const* d_in, const int* in_sizes, int n_in, void* d_out,
                              int out_size, void* d_ws, size_t ws_size, hipStream_t stream) {
  const float* x = (const float*)d_in[0];
  const float* Wp = (const float*)d_in[1];
  const float* bp = (const float*)d_in[2];
  const float* tw = (const float*)d_in[3];
  const float* Wo = (const float*)d_in[4];
  const float* bo = (const float*)d_in[5];
  float* out = (float*)d_out;

  char* ws = (char*)d_ws;
  // layout (bytes): [0,16M) xT / mixedT (reused)  [16M,32M) proj
  //                 [32M,34M) WpB  [34M,36M) WoB  [36M,+0.6M) Gr8
  unsigned short* xT = (unsigned short*)(ws);  // also mixedT after stage 2
  unsigned short* proj = (unsigned short*)(ws + (16ull << 20));
  unsigned short* WpB = (unsigned short*)(ws + (32ull << 20));
  unsigned short* WoB = (unsigned short*)(ws + (34ull << 20));
  unsigned short* Gr8 = (unsigned short*)(ws + (36ull << 20));

  prep_kernel<<<dim3(2048), 256, 0, stream>>>(Wp, Wo, tw, WpB, WoB, Gr8);
  transpose_cast<<<dim3(NT / 32, ND / 32, NB), 256, 0, stream>>>(x, xT);
  // stage 1: proj[b][he][t] = Wp @ x[b] + bp
  gemm_bt<true><<<dim3(16, 8, NB), 256, 0, stream>>>(WpB, xT, bp, proj, (long)NT * ND,
                                                     (long)ND * NT);
  // stage 2: mixedT[b][t][he] (written into xT buffer)
  toeplitz<<<dim3(NT / 128, NH, NB / 2), 256, 0, stream>>>(proj, Gr8, xT);
  // stage 3: out[b][d][t] = Wo @ mixedT[b]^T + bo
  gemm_bt<false><<<dim3(16, 8, NB), 256, 0, stream>>>(WoB, xT, bo, out, (long)NT * ND,
                                                      (long)ND * NT);
}

// Round 4
// 176.402 us; speedup vs baseline: 1.3167x; 1.0735x over previous
//
#include <hip/hip_runtime.h>
#include <cstdint>

#define NB 4
#define ND 1024
#define NT 2048
#define NH 16
#define NE 64
#define GLEN 2240  // per-copy length of reversed global Toeplitz table (elements)
#define CAP 2312   // per-copy length of LDS table (elements)

typedef __bf16 bf16x8 __attribute__((ext_vector_type(8)));
typedef float f32x4 __attribute__((ext_vector_type(4)));
typedef unsigned short us8 __attribute__((ext_vector_type(8)));

__device__ __forceinline__ unsigned short f2bf(float f) {
  unsigned u = __builtin_bit_cast(unsigned, f);
  return (unsigned short)((u + 0x7fffu + ((u >> 16) & 1u)) >> 16);  // RTNE
}

// async global->LDS, 16B per lane; LDS dest must be wave-uniform base + lane*16
__device__ __forceinline__ void gload16(const void* g, void* l) {
  __builtin_amdgcn_global_load_lds(
      (const __attribute__((address_space(1))) void*)(uintptr_t)g,
      (__attribute__((address_space(3))) void*)(uintptr_t)l, 16, 0, 0);
}

// ---------------------------------------------------------------- prep ------
// Cast Wp, Wo to bf16; build 8-copy reversed Toeplitz table:
//   R[c] = bf16(tw[h][2047-c]) for c<=2047 else 0   (c>2047 <=> t-s<0: causal 0)
//   Gr8[h][r][i] = R[i+r]  so any 8-consecutive-element read lands 16B-aligned
//   in copy r = start&7.
__global__ void prep_kernel(const float* __restrict__ Wp, const float* __restrict__ Wo,
                            const float* __restrict__ tw,
                            unsigned short* __restrict__ WpB, unsigned short* __restrict__ WoB,
                            unsigned short* __restrict__ Gr8) {
  int idx = blockIdx.x * 256 + threadIdx.x;
  int stride = gridDim.x * 256;
  for (int i = idx; i < ND * ND; i += stride) WpB[i] = f2bf(Wp[i]);
  for (int i = idx; i < ND * ND; i += stride) WoB[i] = f2bf(Wo[i]);
  for (int i = idx; i < NH * 8 * GLEN; i += stride) {
    int h = i / (8 * GLEN);
    int rem = i - h * 8 * GLEN;
    int r = rem / GLEN;
    int c = rem - r * GLEN;
    int src = c + r;
    Gr8[i] = (src <= NT - 1) ? f2bf(tw[h * NT + (NT - 1) - src]) : (unsigned short)0;
  }
}

// ------------------------------------------------------- transpose + cast ---
// x (B,D,T) f32 -> xT (B,T,D) bf16. 32x32 LDS tile.
__global__ __launch_bounds__(256) void transpose_cast(const float* __restrict__ x,
                                                      unsigned short* __restrict__ xT) {
  __shared__ float tile[32][33];
  int tx = threadIdx.x & 31, ty = threadIdx.x >> 5;  // ty in 0..7
  int t0 = blockIdx.x * 32, d0 = blockIdx.y * 32, b = blockIdx.z;
  const float* xb = x + (long)b * ND * NT;
#pragma unroll
  for (int k = 0; k < 4; ++k)
    tile[ty + 8 * k][tx] = xb[(long)(d0 + ty + 8 * k) * NT + t0 + tx];
  __syncthreads();
  unsigned short* xTb = xT + (long)b * NT * ND;
#pragma unroll
  for (int k = 0; k < 4; ++k)
    xTb[(long)(t0 + ty + 8 * k) * ND + d0 + tx] = f2bf(tile[tx][ty + 8 * k]);
}

// ----------------------------------------------------------- gemm_bt --------
// C[b][m][n] = sum_k A[m][k] * Bt[b][n][k] + bias[m]
// M=1024, N=2048, K=1024. 128x128 tile, BK=32, 4 waves of 64x64, 16x16x32 MFMA.
template <bool OUT_BF16>
__global__ __launch_bounds__(256, 2) void gemm_bt(const unsigned short* __restrict__ A,
                                                  const unsigned short* __restrict__ Bt,
                                                  const float* __restrict__ bias,
                                                  void* __restrict__ Cb, long strideB,
                                                  long strideC) {
  const int N = 2048, K = 1024;
  __shared__ __align__(16) unsigned short As[128 * 32];
  __shared__ __align__(16) unsigned short Bs[128 * 32];
  const int tid = threadIdx.x;
  const int lane = tid & 63;
  const int wid = tid >> 6;
  const int wm = (wid & 1) * 64, wn = (wid >> 1) * 64;
  const int m0 = blockIdx.y * 128, n0 = blockIdx.x * 128;
  const unsigned short* Bb = Bt + (long)blockIdx.z * strideB;
  const int mlo = lane & 15, q = lane >> 4;

  f32x4 acc[4][4] = {};
  for (int k0 = 0; k0 < K; k0 += 32) {
#pragma unroll
    for (int p = 0; p < 2; ++p) {
      int idx = p * 256 + tid;
      int row = idx >> 2, kc = (idx & 3) * 8;
      gload16(A + (long)(m0 + row) * K + k0 + kc, &As[idx * 8]);
      gload16(Bb + (long)(n0 + row) * K + k0 + kc, &Bs[idx * 8]);
    }
    __syncthreads();
    bf16x8 av[4], bv[4];
#pragma unroll
    for (int i = 0; i < 4; ++i) {
      av[i] = __builtin_bit_cast(bf16x8, *(const us8*)&As[(wm + i * 16 + mlo) * 32 + q * 8]);
      bv[i] = __builtin_bit_cast(bf16x8, *(const us8*)&Bs[(wn + i * 16 + mlo) * 32 + q * 8]);
    }
#pragma unroll
    for (int i = 0; i < 4; ++i)
#pragma unroll
      for (int j = 0; j < 4; ++j)
        acc[i][j] = __builtin_amdgcn_mfma_f32_16x16x32_bf16(av[i], bv[j], acc[i][j], 0, 0, 0);
    __syncthreads();
  }
  // epilogue: C/D layout col=lane&15, row=(lane>>4)*4+r
#pragma unroll
  for (int i = 0; i < 4; ++i)
#pragma unroll
    for (int j = 0; j < 4; ++j)
#pragma unroll
      for (int r = 0; r < 4; ++r) {
        int gr = m0 + wm + i * 16 + q * 4 + r;
        int gc = n0 + wn + j * 16 + mlo;
        float v = acc[i][j][r] + bias[gr];
        if (OUT_BF16)
          ((unsigned short*)Cb)[(long)blockIdx.z * strideC + (long)gr * N + gc] = f2bf(v);
        else
          ((float*)Cb)[(long)blockIdx.z * strideC + (long)gr * N + gc] = v;
      }
}

// ----------------------------------------------------------- toeplitz -------
// mixedT[b][t][h*64+e] = sum_{s<=t} tw[h][t-s] * proj[b][h*64+e][s]
// Block = (pair j, h, batch bz): processes t-tile (15-j) then t-tile j,
// each 128t x 64e. Per-block k-iters = 68 for ALL blocks (deterministic
// balance; no dispatch assumptions). One Ls fill serves both phases (all
// R-windows end at index 2176; shorter tile reads at offset +t0L-t0p).
// A-rotation: av[i]@s0 == av[i-2]@(s0-32) -> only 2 new A b128 per iter.
// Bs double-buffered (2x4KB), staged one iter ahead.
__global__ __launch_bounds__(256, 2) void toeplitz(const unsigned short* __restrict__ proj,
                                                   const unsigned short* __restrict__ Gr8,
                                                   unsigned short* __restrict__ mixedT) {
  __shared__ __align__(16) unsigned short Ls[8 * CAP];      // 36992 B
  __shared__ __align__(16) unsigned short Bs[2][64 * 32];   // 8192 B
  const int tid = threadIdx.x, lane = tid & 63, w = tid >> 6;
  const int j = blockIdx.x, h = blockIdx.y, bz = blockIdx.z;
  const int mlo = lane & 15, q = lane >> 4;
  const int wt = (w >> 1) * 64, we = (w & 1) * 32;
  const int t0L = (15 - j) * 128, t0S = j * 128;

  // ---- one-time LDS fill to the long tile's extent
  const int delta = (NT - 128) - t0L;
  const int MUSE = t0L + 256;
#pragma unroll 1
  for (int r = 0; r < 8; ++r) {
    int rr = (r + delta) & 7;
    int off8 = r + delta - rr;
    const unsigned short* src = Gr8 + (long)(h * 8 + rr) * GLEN + off8;
    unsigned short* dst = &Ls[r * CAP];
    for (int mc = tid; mc * 8 < MUSE; mc += 256) gload16(src + mc * 8, dst + mc * 8);
  }

  const int rA = (7 - mlo) & 7;
  // B staging: thread -> (e-row, k-chunk)
  const int eRow = tid >> 2, kCol = (tid & 3) * 8;
  const unsigned short* bsrc = proj + ((long)bz * ND + h * 64 + eRow) * NT + kCol;

#pragma unroll 1
  for (int p = 0; p < 2; ++p) {
    const int t0p = p ? t0S : t0L;
    const int kend = t0p + 128;  // multiple of 128 -> iters multiple of 4
    const unsigned short* lA =
        &Ls[rA * CAP + (127 - wt - mlo - rA) + q * 8 + (t0L - t0p)];
    gload16(bsrc, &Bs[0][tid * 8]);  // stage s0=0
    __syncthreads();                 // drains fill (p=0) + first stage
    // peel: old A-fragments (i=2,3 at s0=0)
    bf16x8 ap0 = __builtin_bit_cast(bf16x8, *(const us8*)(lA - 32));
    bf16x8 ap1 = __builtin_bit_cast(bf16x8, *(const us8*)(lA - 48));
    f32x4 acc[4][2] = {};
#pragma unroll 1
    for (int s0 = 0; s0 < kend; s0 += 64) {
      // -- sub-iter A: compute on Bs[0]@s0, stage Bs[1]@s0+32 (always in range)
      gload16(bsrc + s0 + 32, &Bs[1][tid * 8]);
      {
        bf16x8 a0 = __builtin_bit_cast(bf16x8, *(const us8*)(lA + s0));
        bf16x8 a1 = __builtin_bit_cast(bf16x8, *(const us8*)(lA + s0 - 16));
        bf16x8 b0 = __builtin_bit_cast(bf16x8, *(const us8*)&Bs[0][(we + mlo) * 32 + q * 8]);
        bf16x8 b1 = __builtin_bit_cast(bf16x8, *(const us8*)&Bs[0][(we + 16 + mlo) * 32 + q * 8]);
        acc[0][0] = __builtin_amdgcn_mfma_f32_16x16x32_bf16(a0, b0, acc[0][0], 0, 0, 0);
        acc[0][1] = __builtin_amdgcn_mfma_f32_16x16x32_bf16(a0, b1, acc[0][1], 0, 0, 0);
        acc[1][0] = __builtin_amdgcn_mfma_f32_16x16x32_bf16(a1, b0, acc[1][0], 0, 0, 0);
        acc[1][1] = __builtin_amdgcn_mfma_f32_16x16x32_bf16(a1, b1, acc[1][1], 0, 0, 0);
        acc[2][0] = __builtin_amdgcn_mfma_f32_16x16x32_bf16(ap0, b0, acc[2][0], 0, 0, 0);
        acc[2][1] = __builtin_amdgcn_mfma_f32_16x16x32_bf16(ap0, b1, acc[2][1], 0, 0, 0);
        acc[3][0] = __builtin_amdgcn_mfma_f32_16x16x32_bf16(ap1, b0, acc[3][0], 0, 0, 0);
        acc[3][1] = __builtin_amdgcn_mfma_f32_16x16x32_bf16(ap1, b1, acc[3][1], 0, 0, 0);
        ap0 = a0;
        ap1 = a1;
      }
      __syncthreads();
      // -- sub-iter B: compute on Bs[1]@s0+32, stage Bs[0]@s0+64 if in range
      if (s0 + 64 < kend) gload16(bsrc + s0 + 64, &Bs[0][tid * 8]);
      {
        bf16x8 a0 = __builtin_bit_cast(bf16x8, *(const us8*)(lA + s0 + 32));
        bf16x8 a1 = __builtin_bit_cast(bf16x8, *(const us8*)(lA + s0 + 16));
        bf16x8 b0 = __builtin_bit_cast(bf16x8, *(const us8*)&Bs[1][(we + mlo) * 32 + q * 8]);
        bf16x8 b1 = __builtin_bit_cast(bf16x8, *(const us8*)&Bs[1][(we + 16 + mlo) * 32 + q * 8]);
        acc[0][0] = __builtin_amdgcn_mfma_f32_16x16x32_bf16(a0, b0, acc[0][0], 0, 0, 0);
        acc[0][1] = __builtin_amdgcn_mfma_f32_16x16x32_bf16(a0, b1, acc[0][1], 0, 0, 0);
        acc[1][0] = __builtin_amdgcn_mfma_f32_16x16x32_bf16(a1, b0, acc[1][0], 0, 0, 0);
        acc[1][1] = __builtin_amdgcn_mfma_f32_16x16x32_bf16(a1, b1, acc[1][1], 0, 0, 0);
        acc[2][0] = __builtin_amdgcn_mfma_f32_16x16x32_bf16(ap0, b0, acc[2][0], 0, 0, 0);
        acc[2][1] = __builtin_amdgcn_mfma_f32_16x16x32_bf16(ap0, b1, acc[2][1], 0, 0, 0);
        acc[3][0] = __builtin_amdgcn_mfma_f32_16x16x32_bf16(ap1, b0, acc[3][0], 0, 0, 0);
        acc[3][1] = __builtin_amdgcn_mfma_f32_16x16x32_bf16(ap1, b1, acc[3][1], 0, 0, 0);
        ap0 = a0;
        ap1 = a1;
      }
      __syncthreads();
    }
    // epilogue for this phase
#pragma unroll
    for (int i = 0; i < 4; ++i)
#pragma unroll
      for (int jj = 0; jj < 2; ++jj)
#pragma unroll
        for (int rr = 0; rr < 4; ++rr) {
          int t = t0p + wt + i * 16 + q * 4 + rr;
          int e = we + jj * 16 + mlo;
          mixedT[((long)bz * NT + t) * ND + h * 64 + e] = f2bf(acc[i][jj][rr]);
        }
  }
}

// ---------------------------------------------------------------------------
extern "C" void kernel_launch(void* const* d_in, const int* in_sizes, int n_in, void* d_out,
                              int out_size, void* d_ws, size_t ws_size, hipStream_t stream) {
  const float* x = (const float*)d_in[0];
  const float* Wp = (const float*)d_in[1];
  const float* bp = (const float*)d_in[2];
  const float* tw = (const float*)d_in[3];
  const float* Wo = (const float*)d_in[4];
  const float* bo = (const float*)d_in[5];
  float* out = (float*)d_out;

  char* ws = (char*)d_ws;
  // layout (bytes): [0,16M) xT / mixedT (reused)  [16M,32M) proj
  //                 [32M,34M) WpB  [34M,36M) WoB  [36M,+0.6M) Gr8
  unsigned short* xT = (unsigned short*)(ws);  // also mixedT after stage 2
  unsigned short* proj = (unsigned short*)(ws + (16ull << 20));
  unsigned short* WpB = (unsigned short*)(ws + (32ull << 20));
  unsigned short* WoB = (unsigned short*)(ws + (34ull << 20));
  unsigned short* Gr8 = (unsigned short*)(ws + (36ull << 20));

  prep_kernel<<<dim3(2048), 256, 0, stream>>>(Wp, Wo, tw, WpB, WoB, Gr8);
  transpose_cast<<<dim3(NT / 32, ND / 32, NB), 256, 0, stream>>>(x, xT);
  // stage 1: proj[b][he][t] = Wp @ x[b] + bp
  gemm_bt<true><<<dim3(16, 8, NB), 256, 0, stream>>>(WpB, xT, bp, proj, (long)NT * ND,
                                                     (long)ND * NT);
  // stage 2: mixedT[b][t][he] (written into xT buffer)
  toeplitz<<<dim3(8, NH, NB), 256, 0, stream>>>(proj, Gr8, xT);
  // stage 3: out[b][d][t] = Wo @ mixedT[b]^T + bo
  gemm_bt<false><<<dim3(16, 8, NB), 256, 0, stream>>>(WoB, xT, bo, out, (long)NT * ND,
                                                      (long)ND * NT);
}

// Round 5
// 169.400 us; speedup vs baseline: 1.3711x; 1.0413x over previous
//
#include <hip/hip_runtime.h>
#include <cstdint>

#define NB 4
#define ND 1024
#define NT 2048
#define NH 16
#define NE 64
#define GLEN 2240  // per-copy length of reversed global Toeplitz table (elements)
#define CAP 2312   // per-copy length of LDS table (elements)

typedef __bf16 bf16x8 __attribute__((ext_vector_type(8)));
typedef float f32x4 __attribute__((ext_vector_type(4)));
typedef unsigned short us8 __attribute__((ext_vector_type(8)));
typedef unsigned short us4 __attribute__((ext_vector_type(4)));

__device__ __forceinline__ unsigned short f2bf(float f) {
  unsigned u = __builtin_bit_cast(unsigned, f);
  return (unsigned short)((u + 0x7fffu + ((u >> 16) & 1u)) >> 16);  // RTNE
}

// async global->LDS, 16B per lane; LDS dest must be wave-uniform base + lane*16
__device__ __forceinline__ void gload16(const void* g, void* l) {
  __builtin_amdgcn_global_load_lds(
      (const __attribute__((address_space(1))) void*)(uintptr_t)g,
      (__attribute__((address_space(3))) void*)(uintptr_t)l, 16, 0, 0);
}

// ---------------------------------------------------------------- prep ------
// Cast Wp, Wo to bf16 (vectorized); build 8-copy reversed Toeplitz table:
//   R[c] = bf16(tw[h][2047-c]) for c<=2047 else 0   (c>2047 <=> t-s<0: causal 0)
//   Gr8[h][r][i] = R[i+r]  so any 8-consecutive-element read lands 16B-aligned
//   in copy r = start&7.
__global__ void prep_kernel(const float* __restrict__ Wp, const float* __restrict__ Wo,
                            const float* __restrict__ tw,
                            unsigned short* __restrict__ WpB, unsigned short* __restrict__ WoB,
                            unsigned short* __restrict__ Gr8) {
  int idx = blockIdx.x * 256 + threadIdx.x;
  int stride = gridDim.x * 256;
  const int n4 = ND * ND / 4;
  for (int i = idx; i < n4; i += stride) {
    float4 v = ((const float4*)Wp)[i];
    us4 o = {f2bf(v.x), f2bf(v.y), f2bf(v.z), f2bf(v.w)};
    ((us4*)WpB)[i] = o;
  }
  for (int i = idx; i < n4; i += stride) {
    float4 v = ((const float4*)Wo)[i];
    us4 o = {f2bf(v.x), f2bf(v.y), f2bf(v.z), f2bf(v.w)};
    ((us4*)WoB)[i] = o;
  }
  for (int i = idx; i < NH * 8 * GLEN; i += stride) {
    int h = i / (8 * GLEN);
    int rem = i - h * 8 * GLEN;
    int r = rem / GLEN;
    int c = rem - r * GLEN;
    int src = c + r;
    Gr8[i] = (src <= NT - 1) ? f2bf(tw[h * NT + (NT - 1) - src]) : (unsigned short)0;
  }
}

// ------------------------------------------------------- transpose + cast ---
// x (B,D,T) f32 -> xT (B,T,D) bf16. 64x64 tile; float4 loads (256B/wave),
// us4 8B stores; stride-65 LDS rows keep conflicts at free 2-way.
__global__ __launch_bounds__(256) void transpose_cast(const float* __restrict__ x,
                                                      unsigned short* __restrict__ xT) {
  __shared__ float tile[64][65];
  const int c = threadIdx.x & 15, r = threadIdx.x >> 4;  // c: 16 col-chunks, r: 16 rows
  const int t0 = blockIdx.x * 64, d0 = blockIdx.y * 64, b = blockIdx.z;
  const float* xb = x + (long)b * ND * NT;
#pragma unroll
  for (int k = 0; k < 4; ++k) {
    float4 v = *(const float4*)&xb[(long)(d0 + r + 16 * k) * NT + t0 + 4 * c];
    tile[r + 16 * k][4 * c + 0] = v.x;
    tile[r + 16 * k][4 * c + 1] = v.y;
    tile[r + 16 * k][4 * c + 2] = v.z;
    tile[r + 16 * k][4 * c + 3] = v.w;
  }
  __syncthreads();
  unsigned short* xTb = xT + (long)b * NT * ND;
#pragma unroll
  for (int k = 0; k < 4; ++k) {
    int t = r + 16 * k;
    us4 o = {f2bf(tile[4 * c + 0][t]), f2bf(tile[4 * c + 1][t]), f2bf(tile[4 * c + 2][t]),
             f2bf(tile[4 * c + 3][t])};
    *(us4*)&xTb[(long)(t0 + t) * ND + d0 + 4 * c] = o;
  }
}

// ----------------------------------------------------------- gemm_bt --------
// C[b][m][n] = sum_k A[m][k] * Bt[b][n][k] + bias[m]
// M=1024, N=2048, K=1024. 128x128 tile, BK=32, 4 waves of 64x64, 16x16x32 MFMA.
// Double-buffered LDS: stage k+32 right after the barrier, compute on the
// other buffer -> one barrier per BK and a full MFMA phase to hide staging.
template <bool OUT_BF16>
__global__ __launch_bounds__(256, 3) void gemm_bt(const unsigned short* __restrict__ A,
                                                  const unsigned short* __restrict__ Bt,
                                                  const float* __restrict__ bias,
                                                  void* __restrict__ Cb, long strideB,
                                                  long strideC) {
  const int N = 2048, K = 1024;
  __shared__ __align__(16) unsigned short As[2][128 * 32];
  __shared__ __align__(16) unsigned short Bs[2][128 * 32];
  const int tid = threadIdx.x;
  const int lane = tid & 63;
  const int wid = tid >> 6;
  const int wm = (wid & 1) * 64, wn = (wid >> 1) * 64;
  const int m0 = blockIdx.y * 128, n0 = blockIdx.x * 128;
  const unsigned short* Bb = Bt + (long)blockIdx.z * strideB;
  const int mlo = lane & 15, q = lane >> 4;

  f32x4 acc[4][4] = {};
  auto stage = [&](int buf, int k0) {
#pragma unroll
    for (int p = 0; p < 2; ++p) {
      int idx = p * 256 + tid;
      int row = idx >> 2, kc = (idx & 3) * 8;
      gload16(A + (long)(m0 + row) * K + k0 + kc, &As[buf][idx * 8]);
      gload16(Bb + (long)(n0 + row) * K + k0 + kc, &Bs[buf][idx * 8]);
    }
  };
  auto compute = [&](int buf) {
    bf16x8 av[4], bv[4];
#pragma unroll
    for (int i = 0; i < 4; ++i) {
      av[i] = __builtin_bit_cast(bf16x8, *(const us8*)&As[buf][(wm + i * 16 + mlo) * 32 + q * 8]);
      bv[i] = __builtin_bit_cast(bf16x8, *(const us8*)&Bs[buf][(wn + i * 16 + mlo) * 32 + q * 8]);
    }
#pragma unroll
    for (int i = 0; i < 4; ++i)
#pragma unroll
      for (int j = 0; j < 4; ++j)
        acc[i][j] = __builtin_amdgcn_mfma_f32_16x16x32_bf16(av[i], bv[j], acc[i][j], 0, 0, 0);
  };

  stage(0, 0);
#pragma unroll 1
  for (int k0 = 0; k0 < K; k0 += 64) {
    __syncthreads();          // stage(0)@k0 landed; prior readers of As[1] done
    stage(1, k0 + 32);        // K multiple of 64 -> always in range
    compute(0);
    __syncthreads();          // stage(1) landed; readers of As[0] done
    if (k0 + 64 < K) stage(0, k0 + 64);
    compute(1);
  }
  // epilogue: C/D layout col=lane&15, row=(lane>>4)*4+r
#pragma unroll
  for (int i = 0; i < 4; ++i)
#pragma unroll
    for (int j = 0; j < 4; ++j)
#pragma unroll
      for (int r = 0; r < 4; ++r) {
        int gr = m0 + wm + i * 16 + q * 4 + r;
        int gc = n0 + wn + j * 16 + mlo;
        float v = acc[i][j][r] + bias[gr];
        if (OUT_BF16)
          ((unsigned short*)Cb)[(long)blockIdx.z * strideC + (long)gr * N + gc] = f2bf(v);
        else
          ((float*)Cb)[(long)blockIdx.z * strideC + (long)gr * N + gc] = v;
      }
}

// ----------------------------------------------------------- toeplitz -------
// mixedT[b][t][h*64+e] = sum_{s<=t} tw[h][t-s] * proj[b][h*64+e][s]
// Block = (pair j, h, batch bz): processes t-tile (15-j) then t-tile j,
// each 128t x 64e. Per-block k-iters = 68 for ALL blocks (deterministic
// balance). One Ls fill serves both phases. A-rotation: av[i]@s0 ==
// av[i-2]@(s0-32) -> only 2 new A b128 per iter. Bs double-buffered.
__global__ __launch_bounds__(256, 2) void toeplitz(const unsigned short* __restrict__ proj,
                                                   const unsigned short* __restrict__ Gr8,
                                                   unsigned short* __restrict__ mixedT) {
  __shared__ __align__(16) unsigned short Ls[8 * CAP];     // 36992 B
  __shared__ __align__(16) unsigned short Bs[2][64 * 32];  // 8192 B
  const int tid = threadIdx.x, lane = tid & 63, w = tid >> 6;
  const int j = blockIdx.x, h = blockIdx.y, bz = blockIdx.z;
  const int mlo = lane & 15, q = lane >> 4;
  const int wt = (w >> 1) * 64, we = (w & 1) * 32;
  const int t0L = (15 - j) * 128, t0S = j * 128;

  // ---- one-time LDS fill to the long tile's extent
  const int delta = (NT - 128) - t0L;
  const int MUSE = t0L + 256;
#pragma unroll 1
  for (int r = 0; r < 8; ++r) {
    int rr = (r + delta) & 7;
    int off8 = r + delta - rr;
    const unsigned short* src = Gr8 + (long)(h * 8 + rr) * GLEN + off8;
    unsigned short* dst = &Ls[r * CAP];
    for (int mc = tid; mc * 8 < MUSE; mc += 256) gload16(src + mc * 8, dst + mc * 8);
  }

  const int rA = (7 - mlo) & 7;
  const int eRow = tid >> 2, kCol = (tid & 3) * 8;
  const unsigned short* bsrc = proj + ((long)bz * ND + h * 64 + eRow) * NT + kCol;

#pragma unroll 1
  for (int p = 0; p < 2; ++p) {
    const int t0p = p ? t0S : t0L;
    const int kend = t0p + 128;
    const unsigned short* lA = &Ls[rA * CAP + (127 - wt - mlo - rA) + q * 8 + (t0L - t0p)];
    gload16(bsrc, &Bs[0][tid * 8]);  // stage s0=0
    __syncthreads();                 // drains fill (p=0) + first stage
    bf16x8 ap0 = __builtin_bit_cast(bf16x8, *(const us8*)(lA - 32));
    bf16x8 ap1 = __builtin_bit_cast(bf16x8, *(const us8*)(lA - 48));
    f32x4 acc[4][2] = {};
#pragma unroll 1
    for (int s0 = 0; s0 < kend; s0 += 64) {
      gload16(bsrc + s0 + 32, &Bs[1][tid * 8]);
      {
        bf16x8 a0 = __builtin_bit_cast(bf16x8, *(const us8*)(lA + s0));
        bf16x8 a1 = __builtin_bit_cast(bf16x8, *(const us8*)(lA + s0 - 16));
        bf16x8 b0 = __builtin_bit_cast(bf16x8, *(const us8*)&Bs[0][(we + mlo) * 32 + q * 8]);
        bf16x8 b1 = __builtin_bit_cast(bf16x8, *(const us8*)&Bs[0][(we + 16 + mlo) * 32 + q * 8]);
        acc[0][0] = __builtin_amdgcn_mfma_f32_16x16x32_bf16(a0, b0, acc[0][0], 0, 0, 0);
        acc[0][1] = __builtin_amdgcn_mfma_f32_16x16x32_bf16(a0, b1, acc[0][1], 0, 0, 0);
        acc[1][0] = __builtin_amdgcn_mfma_f32_16x16x32_bf16(a1, b0, acc[1][0], 0, 0, 0);
        acc[1][1] = __builtin_amdgcn_mfma_f32_16x16x32_bf16(a1, b1, acc[1][1], 0, 0, 0);
        acc[2][0] = __builtin_amdgcn_mfma_f32_16x16x32_bf16(ap0, b0, acc[2][0], 0, 0, 0);
        acc[2][1] = __builtin_amdgcn_mfma_f32_16x16x32_bf16(ap0, b1, acc[2][1], 0, 0, 0);
        acc[3][0] = __builtin_amdgcn_mfma_f32_16x16x32_bf16(ap1, b0, acc[3][0], 0, 0, 0);
        acc[3][1] = __builtin_amdgcn_mfma_f32_16x16x32_bf16(ap1, b1, acc[3][1], 0, 0, 0);
        ap0 = a0;
        ap1 = a1;
      }
      __syncthreads();
      if (s0 + 64 < kend) gload16(bsrc + s0 + 64, &Bs[0][tid * 8]);
      {
        bf16x8 a0 = __builtin_bit_cast(bf16x8, *(const us8*)(lA + s0 + 32));
        bf16x8 a1 = __builtin_bit_cast(bf16x8, *(const us8*)(lA + s0 + 16));
        bf16x8 b0 = __builtin_bit_cast(bf16x8, *(const us8*)&Bs[1][(we + mlo) * 32 + q * 8]);
        bf16x8 b1 = __builtin_bit_cast(bf16x8, *(const us8*)&Bs[1][(we + 16 + mlo) * 32 + q * 8]);
        acc[0][0] = __builtin_amdgcn_mfma_f32_16x16x32_bf16(a0, b0, acc[0][0], 0, 0, 0);
        acc[0][1] = __builtin_amdgcn_mfma_f32_16x16x32_bf16(a0, b1, acc[0][1], 0, 0, 0);
        acc[1][0] = __builtin_amdgcn_mfma_f32_16x16x32_bf16(a1, b0, acc[1][0], 0, 0, 0);
        acc[1][1] = __builtin_amdgcn_mfma_f32_16x16x32_bf16(a1, b1, acc[1][1], 0, 0, 0);
        acc[2][0] = __builtin_amdgcn_mfma_f32_16x16x32_bf16(ap0, b0, acc[2][0], 0, 0, 0);
        acc[2][1] = __builtin_amdgcn_mfma_f32_16x16x32_bf16(ap0, b1, acc[2][1], 0, 0, 0);
        acc[3][0] = __builtin_amdgcn_mfma_f32_16x16x32_bf16(ap1, b0, acc[3][0], 0, 0, 0);
        acc[3][1] = __builtin_amdgcn_mfma_f32_16x16x32_bf16(ap1, b1, acc[3][1], 0, 0, 0);
        ap0 = a0;
        ap1 = a1;
      }
      __syncthreads();
    }
#pragma unroll
    for (int i = 0; i < 4; ++i)
#pragma unroll
      for (int jj = 0; jj < 2; ++jj)
#pragma unroll
        for (int rr = 0; rr < 4; ++rr) {
          int t = t0p + wt + i * 16 + q * 4 + rr;
          int e = we + jj * 16 + mlo;
          mixedT[((long)bz * NT + t) * ND + h * 64 + e] = f2bf(acc[i][jj][rr]);
        }
  }
}

// ---------------------------------------------------------------------------
extern "C" void kernel_launch(void* const* d_in, const int* in_sizes, int n_in, void* d_out,
                              int out_size, void* d_ws, size_t ws_size, hipStream_t stream) {
  const float* x = (const float*)d_in[0];
  const float* Wp = (const float*)d_in[1];
  const float* bp = (const float*)d_in[2];
  const float* tw = (const float*)d_in[3];
  const float* Wo = (const float*)d_in[4];
  const float* bo = (const float*)d_in[5];
  float* out = (float*)d_out;

  char* ws = (char*)d_ws;
  // layout (bytes): [0,16M) xT / mixedT (reused)  [16M,32M) proj
  //                 [32M,34M) WpB  [34M,36M) WoB  [36M,+0.6M) Gr8
  unsigned short* xT = (unsigned short*)(ws);  // also mixedT after stage 2
  unsigned short* proj = (unsigned short*)(ws + (16ull << 20));
  unsigned short* WpB = (unsigned short*)(ws + (32ull << 20));
  unsigned short* WoB = (unsigned short*)(ws + (34ull << 20));
  unsigned short* Gr8 = (unsigned short*)(ws + (36ull << 20));

  prep_kernel<<<dim3(1024), 256, 0, stream>>>(Wp, Wo, tw, WpB, WoB, Gr8);
  transpose_cast<<<dim3(NT / 64, ND / 64, NB), 256, 0, stream>>>(x, xT);
  // stage 1: proj[b][he][t] = Wp @ x[b] + bp
  gemm_bt<true><<<dim3(16, 8, NB), 256, 0, stream>>>(WpB, xT, bp, proj, (long)NT * ND,
                                                     (long)ND * NT);
  // stage 2: mixedT[b][t][he] (written into xT buffer)
  toeplitz<<<dim3(8, NH, NB), 256, 0, stream>>>(proj, Gr8, xT);
  // stage 3: out[b][d][t] = Wo @ mixedT[b]^T + bo
  gemm_bt<false><<<dim3(16, 8, NB), 256, 0, stream>>>(WoB, xT, bo, out, (long)NT * ND,
                                                      (long)ND * NT);
}

// Round 6
// 166.299 us; speedup vs baseline: 1.3967x; 1.0186x over previous
//
#include <hip/hip_runtime.h>
#include <cstdint>

#define NB 4
#define ND 1024
#define NT 2048
#define NH 16
#define NE 64
#define GLEN 2240  // per-copy length of reversed global Toeplitz table (elements)
#define CAP 2312   // per-copy length of LDS table (elements)

typedef __bf16 bf16x8 __attribute__((ext_vector_type(8)));
typedef float f32x4 __attribute__((ext_vector_type(4)));
typedef unsigned short us8 __attribute__((ext_vector_type(8)));
typedef unsigned short us4 __attribute__((ext_vector_type(4)));

__device__ __forceinline__ unsigned short f2bf(float f) {
  unsigned u = __builtin_bit_cast(unsigned, f);
  return (unsigned short)((u + 0x7fffu + ((u >> 16) & 1u)) >> 16);  // RTNE
}

// async global->LDS, 16B per lane; LDS dest must be wave-uniform base + lane*16
__device__ __forceinline__ void gload16(const void* g, void* l) {
  __builtin_amdgcn_global_load_lds(
      (const __attribute__((address_space(1))) void*)(uintptr_t)g,
      (__attribute__((address_space(3))) void*)(uintptr_t)l, 16, 0, 0);
}

// ---------------------------------------------------------------- prep ------
__global__ void prep_kernel(const float* __restrict__ Wp, const float* __restrict__ Wo,
                            const float* __restrict__ tw,
                            unsigned short* __restrict__ WpB, unsigned short* __restrict__ WoB,
                            unsigned short* __restrict__ Gr8) {
  int idx = blockIdx.x * 256 + threadIdx.x;
  int stride = gridDim.x * 256;
  const int n4 = ND * ND / 4;
  for (int i = idx; i < n4; i += stride) {
    float4 v = ((const float4*)Wp)[i];
    us4 o = {f2bf(v.x), f2bf(v.y), f2bf(v.z), f2bf(v.w)};
    ((us4*)WpB)[i] = o;
  }
  for (int i = idx; i < n4; i += stride) {
    float4 v = ((const float4*)Wo)[i];
    us4 o = {f2bf(v.x), f2bf(v.y), f2bf(v.z), f2bf(v.w)};
    ((us4*)WoB)[i] = o;
  }
  for (int i = idx; i < NH * 8 * GLEN; i += stride) {
    int h = i / (8 * GLEN);
    int rem = i - h * 8 * GLEN;
    int r = rem / GLEN;
    int c = rem - r * GLEN;
    int src = c + r;
    Gr8[i] = (src <= NT - 1) ? f2bf(tw[h * NT + (NT - 1) - src]) : (unsigned short)0;
  }
}

// ------------------------------------------------------- transpose + cast ---
__global__ __launch_bounds__(256) void transpose_cast(const float* __restrict__ x,
                                                      unsigned short* __restrict__ xT) {
  __shared__ float tile[64][65];
  const int c = threadIdx.x & 15, r = threadIdx.x >> 4;
  const int t0 = blockIdx.x * 64, d0 = blockIdx.y * 64, b = blockIdx.z;
  const float* xb = x + (long)b * ND * NT;
#pragma unroll
  for (int k = 0; k < 4; ++k) {
    float4 v = *(const float4*)&xb[(long)(d0 + r + 16 * k) * NT + t0 + 4 * c];
    tile[r + 16 * k][4 * c + 0] = v.x;
    tile[r + 16 * k][4 * c + 1] = v.y;
    tile[r + 16 * k][4 * c + 2] = v.z;
    tile[r + 16 * k][4 * c + 3] = v.w;
  }
  __syncthreads();
  unsigned short* xTb = xT + (long)b * NT * ND;
#pragma unroll
  for (int k = 0; k < 4; ++k) {
    int t = r + 16 * k;
    us4 o = {f2bf(tile[4 * c + 0][t]), f2bf(tile[4 * c + 1][t]), f2bf(tile[4 * c + 2][t]),
             f2bf(tile[4 * c + 3][t])};
    *(us4*)&xTb[(long)(t0 + t) * ND + d0 + 4 * c] = o;
  }
}

// ----------------------------------------------------------- gemm_bt --------
// C[b][m][n] = sum_k A[m][k] * Bt[b][n][k] + bias[m]
// 128x128 tile, BK=64 (two 32-col half-arrays to keep the conflict-free
// stride-32 layout AND gload16's contiguous-dest rule), double-buffered:
// one barrier per 64-K -> 16 barriers total (half of BK=32 version).
template <bool OUT_BF16>
__global__ __launch_bounds__(256, 2) void gemm_bt(const unsigned short* __restrict__ A,
                                                  const unsigned short* __restrict__ Bt,
                                                  const float* __restrict__ bias,
                                                  void* __restrict__ Cb, long strideB,
                                                  long strideC) {
  const int N = 2048, K = 1024;
  __shared__ __align__(16) unsigned short As[2][2][128 * 32];  // [buf][k-half]
  __shared__ __align__(16) unsigned short Bs[2][2][128 * 32];
  const int tid = threadIdx.x;
  const int lane = tid & 63;
  const int wid = tid >> 6;
  const int wm = (wid & 1) * 64, wn = (wid >> 1) * 64;
  const int m0 = blockIdx.y * 128, n0 = blockIdx.x * 128;
  const unsigned short* Bb = Bt + (long)blockIdx.z * strideB;
  const int mlo = lane & 15, q = lane >> 4;

  f32x4 acc[4][4] = {};
  auto stage = [&](int buf, int k0) {
#pragma unroll
    for (int hh = 0; hh < 2; ++hh)
#pragma unroll
      for (int p = 0; p < 2; ++p) {
        int idx = p * 256 + tid;
        int row = idx >> 2, kc = (idx & 3) * 8;
        gload16(A + (long)(m0 + row) * K + k0 + hh * 32 + kc, &As[buf][hh][idx * 8]);
        gload16(Bb + (long)(n0 + row) * K + k0 + hh * 32 + kc, &Bs[buf][hh][idx * 8]);
      }
  };
  auto compute = [&](int buf) {
#pragma unroll
    for (int hh = 0; hh < 2; ++hh) {
      bf16x8 av[4], bv[4];
#pragma unroll
      for (int i = 0; i < 4; ++i) {
        av[i] =
            __builtin_bit_cast(bf16x8, *(const us8*)&As[buf][hh][(wm + i * 16 + mlo) * 32 + q * 8]);
        bv[i] =
            __builtin_bit_cast(bf16x8, *(const us8*)&Bs[buf][hh][(wn + i * 16 + mlo) * 32 + q * 8]);
      }
#pragma unroll
      for (int i = 0; i < 4; ++i)
#pragma unroll
        for (int j = 0; j < 4; ++j)
          acc[i][j] = __builtin_amdgcn_mfma_f32_16x16x32_bf16(av[i], bv[j], acc[i][j], 0, 0, 0);
    }
  };

  stage(0, 0);
#pragma unroll 1
  for (int k0 = 0; k0 < K; k0 += 128) {
    __syncthreads();
    stage(1, k0 + 64);  // K multiple of 128 -> always in range
    compute(0);
    __syncthreads();
    if (k0 + 128 < K) stage(0, k0 + 128);
    compute(1);
  }
  // epilogue: C/D layout col=lane&15, row=(lane>>4)*4+r
#pragma unroll
  for (int i = 0; i < 4; ++i)
#pragma unroll
    for (int j = 0; j < 4; ++j)
#pragma unroll
      for (int r = 0; r < 4; ++r) {
        int gr = m0 + wm + i * 16 + q * 4 + r;
        int gc = n0 + wn + j * 16 + mlo;
        float v = acc[i][j][r] + bias[gr];
        if (OUT_BF16)
          ((unsigned short*)Cb)[(long)blockIdx.z * strideC + (long)gr * N + gc] = f2bf(v);
        else
          ((float*)Cb)[(long)blockIdx.z * strideC + (long)gr * N + gc] = v;
      }
}

// ----------------------------------------------------------- toeplitz -------
// Same structure as R5 but BK=64 per barrier window (two 32-k half-arrays,
// double-buffered): barriers per block 72 -> 36. A-rotation kept: only 2 new
// A ds_read_b128 per 32-k sub-step.
__global__ __launch_bounds__(256, 2) void toeplitz(const unsigned short* __restrict__ proj,
                                                   const unsigned short* __restrict__ Gr8,
                                                   unsigned short* __restrict__ mixedT) {
  __shared__ __align__(16) unsigned short Ls[8 * CAP];        // 36992 B
  __shared__ __align__(16) unsigned short Bs[2][2][64 * 32];  // 16384 B
  const int tid = threadIdx.x, lane = tid & 63, w = tid >> 6;
  const int j = blockIdx.x, h = blockIdx.y, bz = blockIdx.z;
  const int mlo = lane & 15, q = lane >> 4;
  const int wt = (w >> 1) * 64, we = (w & 1) * 32;
  const int t0L = (15 - j) * 128, t0S = j * 128;

  // ---- one-time LDS fill to the long tile's extent
  const int delta = (NT - 128) - t0L;
  const int MUSE = t0L + 256;
#pragma unroll 1
  for (int r = 0; r < 8; ++r) {
    int rr = (r + delta) & 7;
    int off8 = r + delta - rr;
    const unsigned short* src = Gr8 + (long)(h * 8 + rr) * GLEN + off8;
    unsigned short* dst = &Ls[r * CAP];
    for (int mc = tid; mc * 8 < MUSE; mc += 256) gload16(src + mc * 8, dst + mc * 8);
  }

  const int rA = (7 - mlo) & 7;
  const int eRow = tid >> 2, kCol = (tid & 3) * 8;
  const unsigned short* bsrc = proj + ((long)bz * ND + h * 64 + eRow) * NT + kCol;

#pragma unroll 1
  for (int p = 0; p < 2; ++p) {
    const int t0p = p ? t0S : t0L;
    const int kend = t0p + 128;  // multiple of 128
    const unsigned short* lA = &Ls[rA * CAP + (127 - wt - mlo - rA) + q * 8 + (t0L - t0p)];
    gload16(bsrc, &Bs[0][0][tid * 8]);       // s in [0,32)
    gload16(bsrc + 32, &Bs[0][1][tid * 8]);  // s in [32,64)
    __syncthreads();                         // drains fill (p=0) + first stage
    bf16x8 ap0 = __builtin_bit_cast(bf16x8, *(const us8*)(lA - 32));
    bf16x8 ap1 = __builtin_bit_cast(bf16x8, *(const us8*)(lA - 48));
    f32x4 acc[4][2] = {};

    auto sub = [&](int bf, int hh, int s) {
      bf16x8 a0 = __builtin_bit_cast(bf16x8, *(const us8*)(lA + s));
      bf16x8 a1 = __builtin_bit_cast(bf16x8, *(const us8*)(lA + s - 16));
      bf16x8 b0 = __builtin_bit_cast(bf16x8, *(const us8*)&Bs[bf][hh][(we + mlo) * 32 + q * 8]);
      bf16x8 b1 =
          __builtin_bit_cast(bf16x8, *(const us8*)&Bs[bf][hh][(we + 16 + mlo) * 32 + q * 8]);
      acc[0][0] = __builtin_amdgcn_mfma_f32_16x16x32_bf16(a0, b0, acc[0][0], 0, 0, 0);
      acc[0][1] = __builtin_amdgcn_mfma_f32_16x16x32_bf16(a0, b1, acc[0][1], 0, 0, 0);
      acc[1][0] = __builtin_amdgcn_mfma_f32_16x16x32_bf16(a1, b0, acc[1][0], 0, 0, 0);
      acc[1][1] = __builtin_amdgcn_mfma_f32_16x16x32_bf16(a1, b1, acc[1][1], 0, 0, 0);
      acc[2][0] = __builtin_amdgcn_mfma_f32_16x16x32_bf16(ap0, b0, acc[2][0], 0, 0, 0);
      acc[2][1] = __builtin_amdgcn_mfma_f32_16x16x32_bf16(ap0, b1, acc[2][1], 0, 0, 0);
      acc[3][0] = __builtin_amdgcn_mfma_f32_16x16x32_bf16(ap1, b0, acc[3][0], 0, 0, 0);
      acc[3][1] = __builtin_amdgcn_mfma_f32_16x16x32_bf16(ap1, b1, acc[3][1], 0, 0, 0);
      ap0 = a0;
      ap1 = a1;
    };

#pragma unroll 1
    for (int s0 = 0; s0 < kend; s0 += 128) {
      gload16(bsrc + s0 + 64, &Bs[1][0][tid * 8]);
      gload16(bsrc + s0 + 96, &Bs[1][1][tid * 8]);
      sub(0, 0, s0);
      sub(0, 1, s0 + 32);
      __syncthreads();
      if (s0 + 128 < kend) {
        gload16(bsrc + s0 + 128, &Bs[0][0][tid * 8]);
        gload16(bsrc + s0 + 160, &Bs[0][1][tid * 8]);
      }
      sub(1, 0, s0 + 64);
      sub(1, 1, s0 + 96);
      __syncthreads();
    }
#pragma unroll
    for (int i = 0; i < 4; ++i)
#pragma unroll
      for (int jj = 0; jj < 2; ++jj)
#pragma unroll
        for (int rr = 0; rr < 4; ++rr) {
          int t = t0p + wt + i * 16 + q * 4 + rr;
          int e = we + jj * 16 + mlo;
          mixedT[((long)bz * NT + t) * ND + h * 64 + e] = f2bf(acc[i][jj][rr]);
        }
  }
}

// ---------------------------------------------------------------------------
extern "C" void kernel_launch(void* const* d_in, const int* in_sizes, int n_in, void* d_out,
                              int out_size, void* d_ws, size_t ws_size, hipStream_t stream) {
  const float* x = (const float*)d_in[0];
  const float* Wp = (const float*)d_in[1];
  const float* bp = (const float*)d_in[2];
  const float* tw = (const float*)d_in[3];
  const float* Wo = (const float*)d_in[4];
  const float* bo = (const float*)d_in[5];
  float* out = (float*)d_out;

  char* ws = (char*)d_ws;
  unsigned short* xT = (unsigned short*)(ws);  // also mixedT after stage 2
  unsigned short* proj = (unsigned short*)(ws + (16ull << 20));
  unsigned short* WpB = (unsigned short*)(ws + (32ull << 20));
  unsigned short* WoB = (unsigned short*)(ws + (34ull << 20));
  unsigned short* Gr8 = (unsigned short*)(ws + (36ull << 20));

  prep_kernel<<<dim3(1024), 256, 0, stream>>>(Wp, Wo, tw, WpB, WoB, Gr8);
  transpose_cast<<<dim3(NT / 64, ND / 64, NB), 256, 0, stream>>>(x, xT);
  gemm_bt<true><<<dim3(16, 8, NB), 256, 0, stream>>>(WpB, xT, bp, proj, (long)NT * ND,
                                                     (long)ND * NT);
  toeplitz<<<dim3(8, NH, NB), 256, 0, stream>>>(proj, Gr8, xT);
  gemm_bt<false><<<dim3(16, 8, NB), 256, 0, stream>>>(WoB, xT, bo, out, (long)NT * ND,
                                                      (long)ND * NT);
}